// Round 11
// baseline (365.395 us; speedup 1.0000x reference)
//
#include <hip/hip_runtime.h>
#include <math.h>

#define NN 50000
#define EE 600000
#define DD 128
#define GG 64
#define NCLS 10
#define PCHUNK 128
#define SCHUNK 1024
#define NCHUNK ((NN + SCHUNK - 1) / SCHUNK)
#define NTILE (NN / 16)            // 3125 row-tiles, exact

typedef __attribute__((ext_vector_type(8))) __bf16 bf16x8;
typedef __attribute__((ext_vector_type(8))) unsigned short u16x8;
typedef __attribute__((ext_vector_type(4))) float f32x4;

__device__ __forceinline__ unsigned short f2bf(float f) {
    unsigned int u = __float_as_uint(f);
    u += 0x7fff + ((u >> 16) & 1);     // round-to-nearest-even
    return (unsigned short)(u >> 16);
}

__device__ __forceinline__ float bf2f(unsigned short h) {
    return __uint_as_float(((unsigned int)h) << 16);
}

// ---------------- fused prep: zero cnt/gsum + wt convert + x->bf16 ----------

__global__ __launch_bounds__(256) void prep_kernel(
    const float* __restrict__ x,
    const float* __restrict__ wq, const float* __restrict__ wk,
    const float* __restrict__ wv, const float* __restrict__ ws,
    unsigned short* __restrict__ wt, unsigned short* __restrict__ xb,
    int* __restrict__ cnt, float* __restrict__ gsum) {
    int tid = blockIdx.x * 256 + threadIdx.x;
    int TOT = gridDim.x * 256;
    for (int i = tid; i < NN; i += TOT) cnt[i] = 0;
    for (int i = tid; i < GG * DD + GG; i += TOT) gsum[i] = 0.f;
    for (int i = tid; i < 2 * 4 * 16384; i += TOT) {
        int k = i & 127;
        int n = (i >> 7) & 127;
        int lm = i >> 14;
        int l = lm >> 2, m = lm & 3;
        const float* w = (m == 0) ? wq : (m == 1) ? wk : (m == 2) ? wv : ws;
        wt[i] = f2bf(w[l * 16384 + k * 128 + n]);
    }
    const int NV = (int)(((size_t)NN * DD) / 8);    // 800k u16x8 chunks
    for (int i = tid; i < NV; i += TOT) {
        const float* p = x + (size_t)i * 8;
        float4 f0 = *(const float4*)p;
        float4 f1 = *(const float4*)(p + 4);
        u16x8 a8;
        a8[0] = f2bf(f0.x); a8[1] = f2bf(f0.y); a8[2] = f2bf(f0.z); a8[3] = f2bf(f0.w);
        a8[4] = f2bf(f1.x); a8[5] = f2bf(f1.y); a8[6] = f2bf(f1.z); a8[7] = f2bf(f1.w);
        *(u16x8*)(xb + (size_t)i * 8) = a8;
    }
}

// ---------------- CSR build (split chain; beats grid.sync on MI355X, R7) ----

__global__ void hist_kernel(const int* __restrict__ dst, int* __restrict__ cnt, int e) {
    int i = blockIdx.x * blockDim.x + threadIdx.x;
    if (i < e) atomicAdd(&cnt[dst[i]], 1);
}

__global__ __launch_bounds__(1024) void scan1_kernel(const int* __restrict__ cnt,
                                                     int* __restrict__ lexcl,
                                                     int* __restrict__ csum, int n) {
    __shared__ int wsum[16];
    int tid = threadIdx.x;
    int lane = tid & 63, wid = tid >> 6;
    int i = blockIdx.x * SCHUNK + tid;
    int v = (i < n) ? cnt[i] : 0;
    int x = v;
    #pragma unroll
    for (int off = 1; off < 64; off <<= 1) {
        int y = __shfl_up(x, off);
        if (lane >= off) x += y;
    }
    if (lane == 63) wsum[wid] = x;
    __syncthreads();
    if (wid == 0) {
        int ws = (lane < 16) ? wsum[lane] : 0;
        int xs = ws;
        #pragma unroll
        for (int off = 1; off < 16; off <<= 1) {
            int y = __shfl_up(xs, off);
            if (lane >= off) xs += y;
        }
        if (lane < 16) wsum[lane] = xs - ws;
    }
    __syncthreads();
    if (i < n) lexcl[i] = wsum[wid] + x - v;
    if (tid == 1023) csum[blockIdx.x] = wsum[15] + x;
}

__global__ __launch_bounds__(1024) void scan3_kernel(const int* __restrict__ lexcl,
                                                     const int* __restrict__ csum,
                                                     int* __restrict__ indptr,
                                                     int* __restrict__ cursor,
                                                     int n, int total) {
    __shared__ int base_s;
    int t = threadIdx.x;
    if (t < 64) {
        int v = (t < NCHUNK) ? csum[t] : 0;
        int x = v;
        #pragma unroll
        for (int off = 1; off < 64; off <<= 1) {
            int y = __shfl_up(x, off);
            if (t >= off) x += y;
        }
        if (t == (int)blockIdx.x) base_s = x - v;
    }
    __syncthreads();
    int i = blockIdx.x * SCHUNK + t;
    if (i < n) {
        int val = lexcl[i] + base_s;
        indptr[i] = val;
        cursor[i] = val;
    }
    if (i == 0) indptr[n] = total;
}

__global__ void fill_kernel(const int* __restrict__ src, const int* __restrict__ dst,
                            int* __restrict__ cursor, int* __restrict__ esrc, int e) {
    int i = blockIdx.x * blockDim.x + threadIdx.x;
    if (i < e) {
        int pos = atomicAdd(&cursor[dst[i]], 1);
        esrc[pos] = src[i];
    }
}

// ---------------- persistent-wave LDS-free bf16 MFMA GEMM (R10 winner) -----

__global__ __launch_bounds__(256, 4) void gemm_mfma(
    const unsigned short* __restrict__ xa,      // [NN][128] bf16
    const unsigned short* __restrict__ wt,      // [4][128][128] bf16, n-major
    const float* __restrict__ bq, const float* __restrict__ bk,
    const float* __restrict__ bv, const float* __restrict__ bs,
    unsigned short* __restrict__ qb, unsigned short* __restrict__ kb,
    unsigned short* __restrict__ vb, unsigned short* __restrict__ sb) {
    int gw = blockIdx.x * 4 + (threadIdx.x >> 6);   // 0..2047
    int lane = threadIdx.x & 63;
    int mat = (gw >> 1) & 3;
    int ch = gw & 1;
    int wseq = gw >> 3;                              // 0..255
    int lr = lane & 15, quad = lane >> 4;

    const unsigned short* wm_ = wt + mat * 16384;
    const float* bias = (mat == 0) ? bq : (mat == 1) ? bk : (mat == 2) ? bv : bs;
    unsigned short* outp = (mat == 0) ? qb : (mat == 1) ? kb : (mat == 2) ? vb : sb;

    bf16x8 bfr[4][4];
    #pragma unroll
    for (int ks = 0; ks < 4; ++ks)
        #pragma unroll
        for (int tn = 0; tn < 4; ++tn)
            bfr[ks][tn] = *(const bf16x8*)(wm_ + (ch * 64 + tn * 16 + lr) * 128
                                               + ks * 32 + quad * 8);
    float bcol[4];
    #pragma unroll
    for (int tn = 0; tn < 4; ++tn) bcol[tn] = bias[ch * 64 + tn * 16 + lr];

    for (int tile = wseq; tile < NTILE; tile += 256) {
        int row0 = tile * 16;
        bf16x8 af[4];
        #pragma unroll
        for (int ks = 0; ks < 4; ++ks)
            af[ks] = *(const bf16x8*)(xa + (size_t)(row0 + lr) * DD + ks * 32 + quad * 8);

        f32x4 acc[4];
        #pragma unroll
        for (int tn = 0; tn < 4; ++tn) acc[tn] = (f32x4){0.f, 0.f, 0.f, 0.f};
        #pragma unroll
        for (int ks = 0; ks < 4; ++ks)
            #pragma unroll
            for (int tn = 0; tn < 4; ++tn)
                acc[tn] = __builtin_amdgcn_mfma_f32_16x16x32_bf16(
                    af[ks], bfr[ks][tn], acc[tn], 0, 0, 0);

        #pragma unroll
        for (int tn = 0; tn < 4; ++tn) {
            int col = ch * 64 + tn * 16 + lr;
            int nb = row0 + quad * 4;
            #pragma unroll
            for (int r = 0; r < 4; ++r)
                outp[(size_t)(nb + r) * DD + col] = f2bf(acc[tn][r] + bcol[tn]);
        }
    }
}

// ---------------- attention pass A: scores + softmax stats (k-only gather) --

__global__ __launch_bounds__(256) void attn_score(
    const unsigned short* __restrict__ qb, const unsigned short* __restrict__ kb,
    const int* __restrict__ indptr, const int* __restrict__ esrc,
    float* __restrict__ score, float* __restrict__ mnode,
    float* __restrict__ dinv, int n) {
    int node = (int)((blockIdx.x * blockDim.x + threadIdx.x) >> 6);
    int lane = threadIdx.x & 63;
    if (node >= n) return;
    int g = lane >> 4, j = lane & 15;

    u16x8 q8 = *(const u16x8*)(qb + (size_t)node * DD + j * 8);
    float qf[8];
    #pragma unroll
    for (int c = 0; c < 8; ++c) qf[c] = bf2f(q8[c]);

    int beg = indptr[node], end = indptr[node + 1];

    float m = -3.0e38f, den = 0.f;
    for (int e = beg + g; e < end; e += 4) {
        int sidx = esrc[e];
        u16x8 k8 = *(const u16x8*)(kb + (size_t)sidx * DD + j * 8);
        float p;
        p  = qf[0] * bf2f(k8[0]);
        p  = fmaf(qf[1], bf2f(k8[1]), p);
        p  = fmaf(qf[2], bf2f(k8[2]), p);
        p  = fmaf(qf[3], bf2f(k8[3]), p);
        p  = fmaf(qf[4], bf2f(k8[4]), p);
        p  = fmaf(qf[5], bf2f(k8[5]), p);
        p  = fmaf(qf[6], bf2f(k8[6]), p);
        p  = fmaf(qf[7], bf2f(k8[7]), p);
        p += __shfl_xor(p, 8);
        p += __shfl_xor(p, 4);
        p += __shfl_xor(p, 2);
        p += __shfl_xor(p, 1);
        float sc = p * 0.088388347648318447f;   // 1/sqrt(128)
        if (j == 0) score[e] = sc;
        float mn = fmaxf(m, sc);
        den = den * __expf(m - mn) + __expf(sc - mn);
        m = mn;
    }

    // merge the 4 subgroup stats
    float mo = __shfl_xor(m, 16);
    float m2 = fmaxf(m, mo);
    mo = __shfl_xor(m2, 32);
    float mf = fmaxf(m2, mo);
    den *= __expf(m - mf);
    den += __shfl_xor(den, 16);
    den += __shfl_xor(den, 32);
    if (lane == 0) {
        mnode[node] = mf;
        dinv[node] = den > 0.f ? 1.0f / den : 0.f;
    }
}

// ---------------- attention pass B: weighted aggregate (v-only gather) ------
// alpha known per edge -> no rescale chain; 8 independent FMAs per edge.

__global__ __launch_bounds__(256) void attn_agg(
    const unsigned short* __restrict__ vb, const unsigned short* __restrict__ sb,
    const int* __restrict__ indptr, const int* __restrict__ esrc,
    const float* __restrict__ score, const float* __restrict__ mnode,
    const float* __restrict__ dinv, unsigned short* __restrict__ hout, int n) {
    int node = (int)((blockIdx.x * blockDim.x + threadIdx.x) >> 6);
    int lane = threadIdx.x & 63;
    if (node >= n) return;
    int g = lane >> 4, j = lane & 15;

    float mf = mnode[node];
    float di = dinv[node];
    int beg = indptr[node], end = indptr[node + 1];

    float acc[8];
    #pragma unroll
    for (int c = 0; c < 8; ++c) acc[c] = 0.f;

    for (int e = beg + g; e < end; e += 4) {
        int sidx = esrc[e];
        float al = __expf(score[e] - mf) * di;
        u16x8 v8 = *(const u16x8*)(vb + (size_t)sidx * DD + j * 8);
        #pragma unroll
        for (int c = 0; c < 8; ++c)
            acc[c] = fmaf(al, bf2f(v8[c]), acc[c]);
    }

    #pragma unroll
    for (int c = 0; c < 8; ++c) {
        float a = acc[c];
        a += __shfl_xor(a, 16);
        a += __shfl_xor(a, 32);
        acc[c] = a;
    }
    if (g == 0) {
        u16x8 s8 = *(const u16x8*)(sb + (size_t)node * DD + j * 8);
        u16x8 o8;
        #pragma unroll
        for (int c = 0; c < 8; ++c)
            o8[c] = f2bf(fmaxf(acc[c] + bf2f(s8[c]), 0.f));
        *(u16x8*)(hout + (size_t)node * DD + j * 8) = o8;
    }
}

// ---------------- global mean pool (h bf16): segmented running sum ----------

__global__ __launch_bounds__(128) void pool_kernel(const unsigned short* __restrict__ h,
                                                   const int* __restrict__ batch,
                                                   float* __restrict__ gsum,
                                                   float* __restrict__ gcnt, int n) {
    __shared__ int bsh[PCHUNK];
    int t = threadIdx.x;
    int node0 = blockIdx.x * PCHUNK;
    int nnodes = min(PCHUNK, n - node0);
    if (t < nnodes) bsh[t] = batch[node0 + t];
    __syncthreads();

    int cur = bsh[0];
    float acc = 0.f;
    int cnt = 0;
    for (int j = 0; j < nnodes; ++j) {
        int g = bsh[j];
        float val = bf2f(h[(size_t)(node0 + j) * DD + t]);
        if (g != cur) {
            atomicAdd(&gsum[cur * DD + t], acc);
            if (t == 0) atomicAdd(&gcnt[cur], (float)cnt);
            acc = 0.f; cnt = 0; cur = g;
        }
        acc += val; ++cnt;
    }
    if (cnt > 0) {
        atomicAdd(&gsum[cur * DD + t], acc);
        if (t == 0) atomicAdd(&gcnt[cur], (float)cnt);
    }
}

// ---------------- FC + log_softmax ----------------

__global__ __launch_bounds__(64) void head_kernel(
    const float* __restrict__ gsum, const float* __restrict__ gcnt,
    const float* __restrict__ wfc, const float* __restrict__ bfc,
    float* __restrict__ out) {
    int g = blockIdx.x;
    int lane = threadIdx.x;
    float cnt = fmaxf(gcnt[g], 1.0f);
    float inv = 1.0f / cnt;
    float p0 = gsum[g * DD + lane] * inv;
    float p1 = gsum[g * DD + lane + 64] * inv;
    __shared__ float logits[NCLS];
    for (int c = 0; c < NCLS; ++c) {
        float partial = p0 * wfc[lane * NCLS + c] + p1 * wfc[(lane + 64) * NCLS + c];
        partial += __shfl_xor(partial, 32);
        partial += __shfl_xor(partial, 16);
        partial += __shfl_xor(partial, 8);
        partial += __shfl_xor(partial, 4);
        partial += __shfl_xor(partial, 2);
        partial += __shfl_xor(partial, 1);
        if (lane == 0) logits[c] = partial + bfc[c];
    }
    __syncthreads();
    if (lane == 0) {
        float mx = logits[0];
        for (int c = 1; c < NCLS; ++c) mx = fmaxf(mx, logits[c]);
        float sum = 0.f;
        for (int c = 0; c < NCLS; ++c) sum += expf(logits[c] - mx);
        float lse = mx + logf(sum);
        for (int c = 0; c < NCLS; ++c) out[g * NCLS + c] = logits[c] - lse;
    }
}

// ---------------- launch ----------------

extern "C" void kernel_launch(void* const* d_in, const int* in_sizes, int n_in,
                              void* d_out, int out_size, void* d_ws, size_t ws_size,
                              hipStream_t stream) {
    const float* x     = (const float*)d_in[0];
    const int*   ei    = (const int*)d_in[1];
    const int*   batch = (const int*)d_in[2];
    const float* Wq = (const float*)d_in[3];
    const float* bq = (const float*)d_in[4];
    const float* Wk = (const float*)d_in[5];
    const float* bk = (const float*)d_in[6];
    const float* Wv = (const float*)d_in[7];
    const float* bv = (const float*)d_in[8];
    const float* Ws = (const float*)d_in[9];
    const float* bs = (const float*)d_in[10];
    const float* Wfc = (const float*)d_in[11];
    const float* bfc = (const float*)d_in[12];
    float* out = (float*)d_out;

    const size_t ND = (size_t)NN * DD;
    unsigned short* hbuf = (unsigned short*)d_ws;   // all bf16
    unsigned short* qb = hbuf + ND;
    unsigned short* sb = qb + ND;
    unsigned short* kb = sb + ND;
    unsigned short* vb = kb + ND;
    unsigned short* xb = vb + ND;
    unsigned short* wt = xb + ND;                   // [2][4][128][128] bf16
    int* cnt    = (int*)(wt + 2 * 4 * 16384);
    int* indptr = cnt + NN;
    int* cursor = indptr + NN + 1;
    int* esrc   = cursor + NN;
    int* lexcl  = esrc + EE;
    int* csum   = lexcl + NN;
    float* gsum  = (float*)(csum + NCHUNK);
    float* gcnt  = gsum + GG * DD;
    float* score = gcnt + GG;                       // [EE]
    float* mnode = score + EE;                      // [NN]
    float* dinv  = mnode + NN;                      // [NN]

    const int* src = ei;
    const int* dst = ei + EE;

    prep_kernel<<<1024, 256, 0, stream>>>(x, Wq, Wk, Wv, Ws, wt, xb, cnt, gsum);
    hist_kernel<<<(EE + 255) / 256, 256, 0, stream>>>(dst, cnt, EE);
    scan1_kernel<<<NCHUNK, 1024, 0, stream>>>(cnt, lexcl, csum, NN);
    scan3_kernel<<<NCHUNK, 1024, 0, stream>>>(lexcl, csum, indptr, cursor, NN, EE);
    fill_kernel<<<(EE + 255) / 256, 256, 0, stream>>>(src, dst, cursor, esrc, EE);

    for (int l = 0; l < 2; ++l) {
        size_t bo = (size_t)l * DD;
        const unsigned short* wtl = wt + (size_t)l * 4 * 16384;
        const unsigned short* xa = (l == 0) ? xb : hbuf;
        gemm_mfma<<<512, 256, 0, stream>>>(
            xa, wtl, bq + bo, bk + bo, bv + bo, bs + bo, qb, kb, vb, sb);
        attn_score<<<(NN + 3) / 4, 256, 0, stream>>>(
            qb, kb, indptr, esrc, score, mnode, dinv, NN);
        attn_agg<<<(NN + 3) / 4, 256, 0, stream>>>(
            vb, sb, indptr, esrc, score, mnode, dinv, hbuf, NN);
    }

    pool_kernel<<<(NN + PCHUNK - 1) / PCHUNK, 128, 0, stream>>>(hbuf, batch, gsum, gcnt, NN);
    head_kernel<<<GG, 64, 0, stream>>>(gsum, gcnt, Wfc, bfc, out);
}

// Round 12
// 329.148 us; speedup vs baseline: 1.1101x; 1.1101x over previous
//
#include <hip/hip_runtime.h>
#include <math.h>

#define NN 50000
#define EE 600000
#define DD 128
#define GG 64
#define NCLS 10
#define PCHUNK 128
#define SCHUNK 1024
#define NCHUNK ((NN + SCHUNK - 1) / SCHUNK)
#define NTILE (NN / 16)            // 3125 row-tiles, exact

typedef __attribute__((ext_vector_type(8))) __bf16 bf16x8;
typedef __attribute__((ext_vector_type(8))) unsigned short u16x8;
typedef __attribute__((ext_vector_type(4))) float f32x4;

__device__ __forceinline__ unsigned short f2bf(float f) {
    unsigned int u = __float_as_uint(f);
    u += 0x7fff + ((u >> 16) & 1);     // round-to-nearest-even
    return (unsigned short)(u >> 16);
}

__device__ __forceinline__ float bf2f(unsigned short h) {
    return __uint_as_float(((unsigned int)h) << 16);
}

// ---------------- fused prep: zero cnt/gsum + wt convert + x->bf16 ----------

__global__ __launch_bounds__(256) void prep_kernel(
    const float* __restrict__ x,
    const float* __restrict__ wq, const float* __restrict__ wk,
    const float* __restrict__ wv, const float* __restrict__ ws,
    unsigned short* __restrict__ wt, unsigned short* __restrict__ xb,
    int* __restrict__ cnt, float* __restrict__ gsum) {
    int tid = blockIdx.x * 256 + threadIdx.x;
    int TOT = gridDim.x * 256;
    for (int i = tid; i < NN; i += TOT) cnt[i] = 0;
    for (int i = tid; i < GG * DD + GG; i += TOT) gsum[i] = 0.f;
    for (int i = tid; i < 2 * 4 * 16384; i += TOT) {
        int k = i & 127;
        int n = (i >> 7) & 127;
        int lm = i >> 14;
        int l = lm >> 2, m = lm & 3;
        const float* w = (m == 0) ? wq : (m == 1) ? wk : (m == 2) ? wv : ws;
        wt[i] = f2bf(w[l * 16384 + k * 128 + n]);
    }
    const int NV = (int)(((size_t)NN * DD) / 8);
    for (int i = tid; i < NV; i += TOT) {
        const float* p = x + (size_t)i * 8;
        float4 f0 = *(const float4*)p;
        float4 f1 = *(const float4*)(p + 4);
        u16x8 a8;
        a8[0] = f2bf(f0.x); a8[1] = f2bf(f0.y); a8[2] = f2bf(f0.z); a8[3] = f2bf(f0.w);
        a8[4] = f2bf(f1.x); a8[5] = f2bf(f1.y); a8[6] = f2bf(f1.z); a8[7] = f2bf(f1.w);
        *(u16x8*)(xb + (size_t)i * 8) = a8;
    }
}

// ---------------- CSR build (split chain; beats grid.sync on MI355X, R7) ----

__global__ void hist_kernel(const int* __restrict__ dst, int* __restrict__ cnt, int e) {
    int i = blockIdx.x * blockDim.x + threadIdx.x;
    if (i < e) atomicAdd(&cnt[dst[i]], 1);
}

__global__ __launch_bounds__(1024) void scan1_kernel(const int* __restrict__ cnt,
                                                     int* __restrict__ lexcl,
                                                     int* __restrict__ csum, int n) {
    __shared__ int wsum[16];
    int tid = threadIdx.x;
    int lane = tid & 63, wid = tid >> 6;
    int i = blockIdx.x * SCHUNK + tid;
    int v = (i < n) ? cnt[i] : 0;
    int x = v;
    #pragma unroll
    for (int off = 1; off < 64; off <<= 1) {
        int y = __shfl_up(x, off);
        if (lane >= off) x += y;
    }
    if (lane == 63) wsum[wid] = x;
    __syncthreads();
    if (wid == 0) {
        int ws = (lane < 16) ? wsum[lane] : 0;
        int xs = ws;
        #pragma unroll
        for (int off = 1; off < 16; off <<= 1) {
            int y = __shfl_up(xs, off);
            if (lane >= off) xs += y;
        }
        if (lane < 16) wsum[lane] = xs - ws;
    }
    __syncthreads();
    if (i < n) lexcl[i] = wsum[wid] + x - v;
    if (tid == 1023) csum[blockIdx.x] = wsum[15] + x;
}

__global__ __launch_bounds__(1024) void scan3_kernel(const int* __restrict__ lexcl,
                                                     const int* __restrict__ csum,
                                                     int* __restrict__ indptr,
                                                     int* __restrict__ cursor,
                                                     int n, int total) {
    __shared__ int base_s;
    int t = threadIdx.x;
    if (t < 64) {
        int v = (t < NCHUNK) ? csum[t] : 0;
        int x = v;
        #pragma unroll
        for (int off = 1; off < 64; off <<= 1) {
            int y = __shfl_up(x, off);
            if (t >= off) x += y;
        }
        if (t == (int)blockIdx.x) base_s = x - v;
    }
    __syncthreads();
    int i = blockIdx.x * SCHUNK + t;
    if (i < n) {
        int val = lexcl[i] + base_s;
        indptr[i] = val;
        cursor[i] = val;
    }
    if (i == 0) indptr[n] = total;
}

__global__ void fill_kernel(const int* __restrict__ src, const int* __restrict__ dst,
                            int* __restrict__ cursor, int* __restrict__ esrc, int e) {
    int i = blockIdx.x * blockDim.x + threadIdx.x;
    if (i < e) {
        int pos = atomicAdd(&cursor[dst[i]], 1);
        esrc[pos] = src[i];
    }
}

// ---------------- persistent-wave LDS-free bf16 MFMA GEMM (R10 winner) -----
// k,v write into interleaved kv[node][256] (k at +0, v at +128) so attention
// computes ONE gather address per edge.

__global__ __launch_bounds__(256, 4) void gemm_mfma(
    const unsigned short* __restrict__ xa,      // [NN][128] bf16
    const unsigned short* __restrict__ wt,      // [4][128][128] bf16, n-major
    const float* __restrict__ bq, const float* __restrict__ bk,
    const float* __restrict__ bv, const float* __restrict__ bs,
    unsigned short* __restrict__ qb, unsigned short* __restrict__ kvb,
    unsigned short* __restrict__ sb) {
    int gw = blockIdx.x * 4 + (threadIdx.x >> 6);   // 0..2047
    int lane = threadIdx.x & 63;
    int mat = (gw >> 1) & 3;
    int ch = gw & 1;
    int wseq = gw >> 3;                              // 0..255
    int lr = lane & 15, quad = lane >> 4;

    const unsigned short* wm_ = wt + mat * 16384;
    const float* bias = (mat == 0) ? bq : (mat == 1) ? bk : (mat == 2) ? bv : bs;
    unsigned short* outp; int ostride, ooff;
    if (mat == 0)      { outp = qb;  ostride = 128; ooff = 0; }
    else if (mat == 1) { outp = kvb; ostride = 256; ooff = 0; }
    else if (mat == 2) { outp = kvb; ostride = 256; ooff = 128; }
    else               { outp = sb;  ostride = 128; ooff = 0; }

    bf16x8 bfr[4][4];
    #pragma unroll
    for (int ks = 0; ks < 4; ++ks)
        #pragma unroll
        for (int tn = 0; tn < 4; ++tn)
            bfr[ks][tn] = *(const bf16x8*)(wm_ + (ch * 64 + tn * 16 + lr) * 128
                                               + ks * 32 + quad * 8);
    float bcol[4];
    #pragma unroll
    for (int tn = 0; tn < 4; ++tn) bcol[tn] = bias[ch * 64 + tn * 16 + lr];

    for (int tile = wseq; tile < NTILE; tile += 256) {
        int row0 = tile * 16;
        bf16x8 af[4];
        #pragma unroll
        for (int ks = 0; ks < 4; ++ks)
            af[ks] = *(const bf16x8*)(xa + (size_t)(row0 + lr) * DD + ks * 32 + quad * 8);

        f32x4 acc[4];
        #pragma unroll
        for (int tn = 0; tn < 4; ++tn) acc[tn] = (f32x4){0.f, 0.f, 0.f, 0.f};
        #pragma unroll
        for (int ks = 0; ks < 4; ++ks)
            #pragma unroll
            for (int tn = 0; tn < 4; ++tn)
                acc[tn] = __builtin_amdgcn_mfma_f32_16x16x32_bf16(
                    af[ks], bfr[ks][tn], acc[tn], 0, 0, 0);

        // C/D layout: col = lane&15, row = quad*4 + reg
        #pragma unroll
        for (int tn = 0; tn < 4; ++tn) {
            int col = ch * 64 + tn * 16 + lr;
            int nb = row0 + quad * 4;
            #pragma unroll
            for (int r = 0; r < 4; ++r)
                outp[(size_t)(nb + r) * ostride + ooff + col] = f2bf(acc[tn][r] + bcol[tn]);
        }
    }
}

// ---------------- fused online-softmax attention, kv interleaved, 2-deep ----
// 4 edges/wave (16-lane subgroups); next edge's kv loaded before current edge
// is processed so the gather latency hides under the dot/exp chain.

__global__ __launch_bounds__(256) void attn_kernel(
    const unsigned short* __restrict__ qb, const unsigned short* __restrict__ kvb,
    const unsigned short* __restrict__ sb,
    const int* __restrict__ indptr, const int* __restrict__ esrc,
    unsigned short* __restrict__ hout, int n) {
    int node = (int)((blockIdx.x * blockDim.x + threadIdx.x) >> 6);
    int lane = threadIdx.x & 63;
    if (node >= n) return;
    int g = lane >> 4, j = lane & 15;

    u16x8 q8 = *(const u16x8*)(qb + (size_t)node * DD + j * 8);
    float qf[8];
    #pragma unroll
    for (int c = 0; c < 8; ++c) qf[c] = bf2f(q8[c]);

    int beg = indptr[node], end = indptr[node + 1];

    float m = -3.0e38f, den = 0.f;
    float acc[8];
    #pragma unroll
    for (int c = 0; c < 8; ++c) acc[c] = 0.f;

    int e = beg + g;
    if (e < end) {
        const unsigned short* p0 = kvb + (size_t)esrc[e] * 256 + j * 8;
        u16x8 k8 = *(const u16x8*)p0;
        u16x8 v8 = *(const u16x8*)(p0 + 128);
        for (;;) {
            int en = e + 4;
            bool haven = en < end;
            u16x8 k8n, v8n;
            if (haven) {
                const unsigned short* p = kvb + (size_t)esrc[en] * 256 + j * 8;
                k8n = *(const u16x8*)p;
                v8n = *(const u16x8*)(p + 128);
            }
            float p_;
            p_ = qf[0] * bf2f(k8[0]);
            p_ = fmaf(qf[1], bf2f(k8[1]), p_);
            p_ = fmaf(qf[2], bf2f(k8[2]), p_);
            p_ = fmaf(qf[3], bf2f(k8[3]), p_);
            p_ = fmaf(qf[4], bf2f(k8[4]), p_);
            p_ = fmaf(qf[5], bf2f(k8[5]), p_);
            p_ = fmaf(qf[6], bf2f(k8[6]), p_);
            p_ = fmaf(qf[7], bf2f(k8[7]), p_);
            p_ += __shfl_xor(p_, 8);
            p_ += __shfl_xor(p_, 4);
            p_ += __shfl_xor(p_, 2);
            p_ += __shfl_xor(p_, 1);
            float score = p_ * 0.088388347648318447f;   // 1/sqrt(128)
            float mn = fmaxf(m, score);
            float scale = __expf(m - mn);
            float pe = __expf(score - mn);
            den = den * scale + pe;
            #pragma unroll
            for (int c = 0; c < 8; ++c)
                acc[c] = fmaf(acc[c], scale, pe * bf2f(v8[c]));
            m = mn;
            if (!haven) break;
            e = en; k8 = k8n; v8 = v8n;
        }
    }

    // merge the 4 subgroup states (finite m0 => no inf-inf NaN)
    float mo = __shfl_xor(m, 16);
    float m2 = fmaxf(m, mo);
    mo = __shfl_xor(m2, 32);
    float mf = fmaxf(m2, mo);
    float sc = __expf(m - mf);
    den *= sc;
    den += __shfl_xor(den, 16);
    den += __shfl_xor(den, 32);
    #pragma unroll
    for (int c = 0; c < 8; ++c) {
        float a = acc[c] * sc;
        a += __shfl_xor(a, 16);
        a += __shfl_xor(a, 32);
        acc[c] = a;
    }
    float inv = den > 0.f ? 1.0f / den : 0.f;
    if (g == 0) {
        u16x8 s8 = *(const u16x8*)(sb + (size_t)node * DD + j * 8);
        u16x8 o8;
        #pragma unroll
        for (int c = 0; c < 8; ++c)
            o8[c] = f2bf(fmaxf(fmaf(acc[c], inv, bf2f(s8[c])), 0.f));
        *(u16x8*)(hout + (size_t)node * DD + j * 8) = o8;
    }
}

// ---------------- global mean pool (h bf16): segmented running sum ----------

__global__ __launch_bounds__(128) void pool_kernel(const unsigned short* __restrict__ h,
                                                   const int* __restrict__ batch,
                                                   float* __restrict__ gsum,
                                                   float* __restrict__ gcnt, int n) {
    __shared__ int bsh[PCHUNK];
    int t = threadIdx.x;
    int node0 = blockIdx.x * PCHUNK;
    int nnodes = min(PCHUNK, n - node0);
    if (t < nnodes) bsh[t] = batch[node0 + t];
    __syncthreads();

    int cur = bsh[0];
    float acc = 0.f;
    int cnt = 0;
    for (int j = 0; j < nnodes; ++j) {
        int g = bsh[j];
        float val = bf2f(h[(size_t)(node0 + j) * DD + t]);
        if (g != cur) {
            atomicAdd(&gsum[cur * DD + t], acc);
            if (t == 0) atomicAdd(&gcnt[cur], (float)cnt);
            acc = 0.f; cnt = 0; cur = g;
        }
        acc += val; ++cnt;
    }
    if (cnt > 0) {
        atomicAdd(&gsum[cur * DD + t], acc);
        if (t == 0) atomicAdd(&gcnt[cur], (float)cnt);
    }
}

// ---------------- FC + log_softmax ----------------

__global__ __launch_bounds__(64) void head_kernel(
    const float* __restrict__ gsum, const float* __restrict__ gcnt,
    const float* __restrict__ wfc, const float* __restrict__ bfc,
    float* __restrict__ out) {
    int g = blockIdx.x;
    int lane = threadIdx.x;
    float cnt = fmaxf(gcnt[g], 1.0f);
    float inv = 1.0f / cnt;
    float p0 = gsum[g * DD + lane] * inv;
    float p1 = gsum[g * DD + lane + 64] * inv;
    __shared__ float logits[NCLS];
    for (int c = 0; c < NCLS; ++c) {
        float partial = p0 * wfc[lane * NCLS + c] + p1 * wfc[(lane + 64) * NCLS + c];
        partial += __shfl_xor(partial, 32);
        partial += __shfl_xor(partial, 16);
        partial += __shfl_xor(partial, 8);
        partial += __shfl_xor(partial, 4);
        partial += __shfl_xor(partial, 2);
        partial += __shfl_xor(partial, 1);
        if (lane == 0) logits[c] = partial + bfc[c];
    }
    __syncthreads();
    if (lane == 0) {
        float mx = logits[0];
        for (int c = 1; c < NCLS; ++c) mx = fmaxf(mx, logits[c]);
        float sum = 0.f;
        for (int c = 0; c < NCLS; ++c) sum += expf(logits[c] - mx);
        float lse = mx + logf(sum);
        for (int c = 0; c < NCLS; ++c) out[g * NCLS + c] = logits[c] - lse;
    }
}

// ---------------- launch ----------------

extern "C" void kernel_launch(void* const* d_in, const int* in_sizes, int n_in,
                              void* d_out, int out_size, void* d_ws, size_t ws_size,
                              hipStream_t stream) {
    const float* x     = (const float*)d_in[0];
    const int*   ei    = (const int*)d_in[1];
    const int*   batch = (const int*)d_in[2];
    const float* Wq = (const float*)d_in[3];
    const float* bq = (const float*)d_in[4];
    const float* Wk = (const float*)d_in[5];
    const float* bk = (const float*)d_in[6];
    const float* Wv = (const float*)d_in[7];
    const float* bv = (const float*)d_in[8];
    const float* Ws = (const float*)d_in[9];
    const float* bs = (const float*)d_in[10];
    const float* Wfc = (const float*)d_in[11];
    const float* bfc = (const float*)d_in[12];
    float* out = (float*)d_out;

    const size_t ND = (size_t)NN * DD;
    unsigned short* hbuf = (unsigned short*)d_ws;   // all bf16
    unsigned short* qb  = hbuf + ND;
    unsigned short* sb  = qb + ND;
    unsigned short* kvb = sb + ND;                  // [NN][256]: k | v interleaved
    unsigned short* xb  = kvb + 2 * ND;
    unsigned short* wt  = xb + ND;                  // [2][4][128][128] bf16
    int* cnt    = (int*)(wt + 2 * 4 * 16384);
    int* indptr = cnt + NN;
    int* cursor = indptr + NN + 1;
    int* esrc   = cursor + NN;
    int* lexcl  = esrc + EE;
    int* csum   = lexcl + NN;
    float* gsum = (float*)(csum + NCHUNK);
    float* gcnt = gsum + GG * DD;

    const int* src = ei;
    const int* dst = ei + EE;

    prep_kernel<<<1024, 256, 0, stream>>>(x, Wq, Wk, Wv, Ws, wt, xb, cnt, gsum);
    hist_kernel<<<(EE + 255) / 256, 256, 0, stream>>>(dst, cnt, EE);
    scan1_kernel<<<NCHUNK, 1024, 0, stream>>>(cnt, lexcl, csum, NN);
    scan3_kernel<<<NCHUNK, 1024, 0, stream>>>(lexcl, csum, indptr, cursor, NN, EE);
    fill_kernel<<<(EE + 255) / 256, 256, 0, stream>>>(src, dst, cursor, esrc, EE);

    for (int l = 0; l < 2; ++l) {
        size_t bo = (size_t)l * DD;
        const unsigned short* wtl = wt + (size_t)l * 4 * 16384;
        const unsigned short* xa = (l == 0) ? xb : hbuf;
        gemm_mfma<<<512, 256, 0, stream>>>(
            xa, wtl, bq + bo, bk + bo, bv + bo, bs + bo, qb, kvb, sb);
        attn_kernel<<<(NN + 3) / 4, 256, 0, stream>>>(
            qb, kvb, sb, indptr, esrc, hbuf, NN);
    }

    pool_kernel<<<(NN + PCHUNK - 1) / PCHUNK, 128, 0, stream>>>(hbuf, batch, gsum, gcnt, NN);
    head_kernel<<<GG, 64, 0, stream>>>(gsum, gcnt, Wfc, bfc, out);
}

// Round 13
// 285.543 us; speedup vs baseline: 1.2796x; 1.1527x over previous
//
#include <hip/hip_runtime.h>
#include <math.h>

#define NN 50000
#define EE 600000
#define DD 128
#define GG 64
#define NCLS 10
#define PCHUNK 128
#define NTILE (NN / 16)            // 3125 row-tiles, exact
#define NBUK 196                   // buckets of 256 dst nodes (dst>>8)
#define BSTRIDE 4096               // slots per bucket (mean 3072, sigma 55)
#define EPB ((EE + 255) / 256)     // 2344 edges per pass-1 block

typedef __attribute__((ext_vector_type(8))) __bf16 bf16x8;
typedef __attribute__((ext_vector_type(8))) unsigned short u16x8;
typedef __attribute__((ext_vector_type(4))) float f32x4;

__device__ __forceinline__ unsigned short f2bf(float f) {
    unsigned int u = __float_as_uint(f);
    u += 0x7fff + ((u >> 16) & 1);     // round-to-nearest-even
    return (unsigned short)(u >> 16);
}

__device__ __forceinline__ float bf2f(unsigned short h) {
    return __uint_as_float(((unsigned int)h) << 16);
}

// ---------------- fused prep: zero bucketcnt/gsum + wt convert + x->bf16 ----

__global__ __launch_bounds__(256) void prep_kernel(
    const float* __restrict__ x,
    const float* __restrict__ wq, const float* __restrict__ wk,
    const float* __restrict__ wv, const float* __restrict__ ws,
    unsigned short* __restrict__ wt, unsigned short* __restrict__ xb,
    int* __restrict__ bucketcnt, float* __restrict__ gsum) {
    int tid = blockIdx.x * 256 + threadIdx.x;
    int TOT = gridDim.x * 256;
    if (tid < 256) bucketcnt[tid] = 0;
    for (int i = tid; i < GG * DD + GG; i += TOT) gsum[i] = 0.f;
    for (int i = tid; i < 2 * 4 * 16384; i += TOT) {
        int k = i & 127;
        int n = (i >> 7) & 127;
        int lm = i >> 14;
        int l = lm >> 2, m = lm & 3;
        const float* w = (m == 0) ? wq : (m == 1) ? wk : (m == 2) ? wv : ws;
        wt[i] = f2bf(w[l * 16384 + k * 128 + n]);
    }
    const int NV = (int)(((size_t)NN * DD) / 8);
    for (int i = tid; i < NV; i += TOT) {
        const float* p = x + (size_t)i * 8;
        float4 f0 = *(const float4*)p;
        float4 f1 = *(const float4*)(p + 4);
        u16x8 a8;
        a8[0] = f2bf(f0.x); a8[1] = f2bf(f0.y); a8[2] = f2bf(f0.z); a8[3] = f2bf(f0.w);
        a8[4] = f2bf(f1.x); a8[5] = f2bf(f1.y); a8[6] = f2bf(f1.z); a8[7] = f2bf(f1.w);
        *(u16x8*)(xb + (size_t)i * 8) = a8;
    }
}

// ---------------- CSR pass 1: bucket by dst>>8 (LDS slots, 65k global atomics)

__global__ __launch_bounds__(1024) void bucket_kernel(
    const int* __restrict__ src, const int* __restrict__ dst,
    int* __restrict__ bucketcnt, int2* __restrict__ bedge) {
    __shared__ int hist[256];
    __shared__ int base[256];
    int t = threadIdx.x;
    if (t < 256) hist[t] = 0;
    __syncthreads();
    int e0 = blockIdx.x * EPB;
    int eend = min(e0 + EPB, EE);

    int b0 = -1, b1 = -1, b2 = -1;
    int sl0 = 0, sl1 = 0, sl2 = 0;
    int s0 = 0, s1 = 0, s2 = 0, d0 = 0, d1 = 0, d2 = 0;
    int i = e0 + t;
    if (i < eend) { d0 = dst[i]; s0 = src[i]; b0 = d0 >> 8; sl0 = atomicAdd(&hist[b0], 1); }
    i += 1024;
    if (i < eend) { d1 = dst[i]; s1 = src[i]; b1 = d1 >> 8; sl1 = atomicAdd(&hist[b1], 1); }
    i += 1024;
    if (i < eend) { d2 = dst[i]; s2 = src[i]; b2 = d2 >> 8; sl2 = atomicAdd(&hist[b2], 1); }
    __syncthreads();

    if (t < 256) {
        int h = hist[t];
        base[t] = h ? atomicAdd(&bucketcnt[t], h) : 0;
    }
    __syncthreads();

    if (b0 >= 0) bedge[b0 * BSTRIDE + base[b0] + sl0] = make_int2(s0, d0);
    if (b1 >= 0) bedge[b1 * BSTRIDE + base[b1] + sl1] = make_int2(s1, d1);
    if (b2 >= 0) bedge[b2 * BSTRIDE + base[b2] + sl2] = make_int2(s2, d2);
}

// ---------------- CSR pass 2: per-bucket node sort -> indptr + esrc ---------

__global__ __launch_bounds__(1024) void bsort_kernel(
    const int* __restrict__ bucketcnt, const int2* __restrict__ bedge,
    int* __restrict__ indptr, int* __restrict__ esrc) {
    __shared__ int buf[256];       // bucket counts, then per-node histogram
    __shared__ int cur[256];       // per-node cursors (exclusive prefix)
    __shared__ int bstart_s;
    int b = blockIdx.x;
    int t = threadIdx.x;

    if (t < 256) buf[t] = (t < NBUK) ? bucketcnt[t] : 0;
    __syncthreads();
    if (t == 0) {
        int acc = 0;
        for (int i2 = 0; i2 < NBUK; ++i2) {
            if (i2 == b) bstart_s = acc;
            acc += buf[i2];
        }
    }
    if (b == 0 && t == 1) indptr[NN] = EE;
    __syncthreads();

    int count = buf[b];
    int node0 = b << 8;
    int nn = min(256, NN - node0);
    __syncthreads();                       // everyone has count before buf reuse
    if (t < 256) buf[t] = 0;
    __syncthreads();

    const int2* be = bedge + (size_t)b * BSTRIDE;
    for (int i2 = t; i2 < count; i2 += 1024)
        atomicAdd(&buf[be[i2].y - node0], 1);
    __syncthreads();

    if (t == 0) {
        int acc = 0;
        for (int i2 = 0; i2 < 256; ++i2) {
            cur[i2] = acc;
            acc += buf[i2];
        }
    }
    __syncthreads();
    if (t < nn) indptr[node0 + t] = bstart_s + cur[t];
    __syncthreads();                       // indptr written before cur mutates

    for (int i2 = t; i2 < count; i2 += 1024) {
        int2 e = be[i2];
        int slot = atomicAdd(&cur[e.y - node0], 1);
        esrc[bstart_s + slot] = e.x;
    }
}

// ---------------- persistent-wave LDS-free bf16 MFMA GEMM (R10 winner) -----
// k,v write into interleaved kv[node][256] (k at +0, v at +128).

__global__ __launch_bounds__(256, 4) void gemm_mfma(
    const unsigned short* __restrict__ xa,      // [NN][128] bf16
    const unsigned short* __restrict__ wt,      // [4][128][128] bf16, n-major
    const float* __restrict__ bq, const float* __restrict__ bk,
    const float* __restrict__ bv, const float* __restrict__ bs,
    unsigned short* __restrict__ qb, unsigned short* __restrict__ kvb,
    unsigned short* __restrict__ sb) {
    int gw = blockIdx.x * 4 + (threadIdx.x >> 6);   // 0..2047
    int lane = threadIdx.x & 63;
    int mat = (gw >> 1) & 3;
    int ch = gw & 1;
    int wseq = gw >> 3;                              // 0..255
    int lr = lane & 15, quad = lane >> 4;

    const unsigned short* wm_ = wt + mat * 16384;
    const float* bias = (mat == 0) ? bq : (mat == 1) ? bk : (mat == 2) ? bv : bs;
    unsigned short* outp; int ostride, ooff;
    if (mat == 0)      { outp = qb;  ostride = 128; ooff = 0; }
    else if (mat == 1) { outp = kvb; ostride = 256; ooff = 0; }
    else if (mat == 2) { outp = kvb; ostride = 256; ooff = 128; }
    else               { outp = sb;  ostride = 128; ooff = 0; }

    bf16x8 bfr[4][4];
    #pragma unroll
    for (int ks = 0; ks < 4; ++ks)
        #pragma unroll
        for (int tn = 0; tn < 4; ++tn)
            bfr[ks][tn] = *(const bf16x8*)(wm_ + (ch * 64 + tn * 16 + lr) * 128
                                               + ks * 32 + quad * 8);
    float bcol[4];
    #pragma unroll
    for (int tn = 0; tn < 4; ++tn) bcol[tn] = bias[ch * 64 + tn * 16 + lr];

    for (int tile = wseq; tile < NTILE; tile += 256) {
        int row0 = tile * 16;
        bf16x8 af[4];
        #pragma unroll
        for (int ks = 0; ks < 4; ++ks)
            af[ks] = *(const bf16x8*)(xa + (size_t)(row0 + lr) * DD + ks * 32 + quad * 8);

        f32x4 acc[4];
        #pragma unroll
        for (int tn = 0; tn < 4; ++tn) acc[tn] = (f32x4){0.f, 0.f, 0.f, 0.f};
        #pragma unroll
        for (int ks = 0; ks < 4; ++ks)
            #pragma unroll
            for (int tn = 0; tn < 4; ++tn)
                acc[tn] = __builtin_amdgcn_mfma_f32_16x16x32_bf16(
                    af[ks], bfr[ks][tn], acc[tn], 0, 0, 0);

        // C/D layout: col = lane&15, row = quad*4 + reg
        #pragma unroll
        for (int tn = 0; tn < 4; ++tn) {
            int col = ch * 64 + tn * 16 + lr;
            int nb = row0 + quad * 4;
            #pragma unroll
            for (int r = 0; r < 4; ++r)
                outp[(size_t)(nb + r) * ostride + ooff + col] = f2bf(acc[tn][r] + bcol[tn]);
        }
    }
}

// ---------------- fused online-softmax attention, kv interleaved, 2-deep ----

__global__ __launch_bounds__(256) void attn_kernel(
    const unsigned short* __restrict__ qb, const unsigned short* __restrict__ kvb,
    const unsigned short* __restrict__ sb,
    const int* __restrict__ indptr, const int* __restrict__ esrc,
    unsigned short* __restrict__ hout, int n) {
    int node = (int)((blockIdx.x * blockDim.x + threadIdx.x) >> 6);
    int lane = threadIdx.x & 63;
    if (node >= n) return;
    int g = lane >> 4, j = lane & 15;

    u16x8 q8 = *(const u16x8*)(qb + (size_t)node * DD + j * 8);
    float qf[8];
    #pragma unroll
    for (int c = 0; c < 8; ++c) qf[c] = bf2f(q8[c]);

    int beg = indptr[node], end = indptr[node + 1];

    float m = -3.0e38f, den = 0.f;
    float acc[8];
    #pragma unroll
    for (int c = 0; c < 8; ++c) acc[c] = 0.f;

    int e = beg + g;
    if (e < end) {
        const unsigned short* p0 = kvb + (size_t)esrc[e] * 256 + j * 8;
        u16x8 k8 = *(const u16x8*)p0;
        u16x8 v8 = *(const u16x8*)(p0 + 128);
        for (;;) {
            int en = e + 4;
            bool haven = en < end;
            u16x8 k8n, v8n;
            if (haven) {
                const unsigned short* p = kvb + (size_t)esrc[en] * 256 + j * 8;
                k8n = *(const u16x8*)p;
                v8n = *(const u16x8*)(p + 128);
            }
            float p_;
            p_ = qf[0] * bf2f(k8[0]);
            p_ = fmaf(qf[1], bf2f(k8[1]), p_);
            p_ = fmaf(qf[2], bf2f(k8[2]), p_);
            p_ = fmaf(qf[3], bf2f(k8[3]), p_);
            p_ = fmaf(qf[4], bf2f(k8[4]), p_);
            p_ = fmaf(qf[5], bf2f(k8[5]), p_);
            p_ = fmaf(qf[6], bf2f(k8[6]), p_);
            p_ = fmaf(qf[7], bf2f(k8[7]), p_);
            p_ += __shfl_xor(p_, 8);
            p_ += __shfl_xor(p_, 4);
            p_ += __shfl_xor(p_, 2);
            p_ += __shfl_xor(p_, 1);
            float score = p_ * 0.088388347648318447f;   // 1/sqrt(128)
            float mn = fmaxf(m, score);
            float scale = __expf(m - mn);
            float pe = __expf(score - mn);
            den = den * scale + pe;
            #pragma unroll
            for (int c = 0; c < 8; ++c)
                acc[c] = fmaf(acc[c], scale, pe * bf2f(v8[c]));
            m = mn;
            if (!haven) break;
            e = en; k8 = k8n; v8 = v8n;
        }
    }

    float mo = __shfl_xor(m, 16);
    float m2 = fmaxf(m, mo);
    mo = __shfl_xor(m2, 32);
    float mf = fmaxf(m2, mo);
    float sc = __expf(m - mf);
    den *= sc;
    den += __shfl_xor(den, 16);
    den += __shfl_xor(den, 32);
    #pragma unroll
    for (int c = 0; c < 8; ++c) {
        float a = acc[c] * sc;
        a += __shfl_xor(a, 16);
        a += __shfl_xor(a, 32);
        acc[c] = a;
    }
    float inv = den > 0.f ? 1.0f / den : 0.f;
    if (g == 0) {
        u16x8 s8 = *(const u16x8*)(sb + (size_t)node * DD + j * 8);
        u16x8 o8;
        #pragma unroll
        for (int c = 0; c < 8; ++c)
            o8[c] = f2bf(fmaxf(fmaf(acc[c], inv, bf2f(s8[c])), 0.f));
        *(u16x8*)(hout + (size_t)node * DD + j * 8) = o8;
    }
}

// ---------------- global mean pool (h bf16): segmented running sum ----------

__global__ __launch_bounds__(128) void pool_kernel(const unsigned short* __restrict__ h,
                                                   const int* __restrict__ batch,
                                                   float* __restrict__ gsum,
                                                   float* __restrict__ gcnt, int n) {
    __shared__ int bsh[PCHUNK];
    int t = threadIdx.x;
    int node0 = blockIdx.x * PCHUNK;
    int nnodes = min(PCHUNK, n - node0);
    if (t < nnodes) bsh[t] = batch[node0 + t];
    __syncthreads();

    int cur = bsh[0];
    float acc = 0.f;
    int cnt = 0;
    for (int j = 0; j < nnodes; ++j) {
        int g = bsh[j];
        float val = bf2f(h[(size_t)(node0 + j) * DD + t]);
        if (g != cur) {
            atomicAdd(&gsum[cur * DD + t], acc);
            if (t == 0) atomicAdd(&gcnt[cur], (float)cnt);
            acc = 0.f; cnt = 0; cur = g;
        }
        acc += val; ++cnt;
    }
    if (cnt > 0) {
        atomicAdd(&gsum[cur * DD + t], acc);
        if (t == 0) atomicAdd(&gcnt[cur], (float)cnt);
    }
}

// ---------------- FC + log_softmax ----------------

__global__ __launch_bounds__(64) void head_kernel(
    const float* __restrict__ gsum, const float* __restrict__ gcnt,
    const float* __restrict__ wfc, const float* __restrict__ bfc,
    float* __restrict__ out) {
    int g = blockIdx.x;
    int lane = threadIdx.x;
    float cnt = fmaxf(gcnt[g], 1.0f);
    float inv = 1.0f / cnt;
    float p0 = gsum[g * DD + lane] * inv;
    float p1 = gsum[g * DD + lane + 64] * inv;
    __shared__ float logits[NCLS];
    for (int c = 0; c < NCLS; ++c) {
        float partial = p0 * wfc[lane * NCLS + c] + p1 * wfc[(lane + 64) * NCLS + c];
        partial += __shfl_xor(partial, 32);
        partial += __shfl_xor(partial, 16);
        partial += __shfl_xor(partial, 8);
        partial += __shfl_xor(partial, 4);
        partial += __shfl_xor(partial, 2);
        partial += __shfl_xor(partial, 1);
        if (lane == 0) logits[c] = partial + bfc[c];
    }
    __syncthreads();
    if (lane == 0) {
        float mx = logits[0];
        for (int c = 1; c < NCLS; ++c) mx = fmaxf(mx, logits[c]);
        float sum = 0.f;
        for (int c = 0; c < NCLS; ++c) sum += expf(logits[c] - mx);
        float lse = mx + logf(sum);
        for (int c = 0; c < NCLS; ++c) out[g * NCLS + c] = logits[c] - lse;
    }
}

// ---------------- launch ----------------

extern "C" void kernel_launch(void* const* d_in, const int* in_sizes, int n_in,
                              void* d_out, int out_size, void* d_ws, size_t ws_size,
                              hipStream_t stream) {
    const float* x     = (const float*)d_in[0];
    const int*   ei    = (const int*)d_in[1];
    const int*   batch = (const int*)d_in[2];
    const float* Wq = (const float*)d_in[3];
    const float* bq = (const float*)d_in[4];
    const float* Wk = (const float*)d_in[5];
    const float* bk = (const float*)d_in[6];
    const float* Wv = (const float*)d_in[7];
    const float* bv = (const float*)d_in[8];
    const float* Ws = (const float*)d_in[9];
    const float* bs = (const float*)d_in[10];
    const float* Wfc = (const float*)d_in[11];
    const float* bfc = (const float*)d_in[12];
    float* out = (float*)d_out;

    const size_t ND = (size_t)NN * DD;
    unsigned short* hbuf = (unsigned short*)d_ws;   // all bf16
    unsigned short* qb  = hbuf + ND;
    unsigned short* sb  = qb + ND;
    unsigned short* kvb = sb + ND;                  // [NN][256]: k | v interleaved
    unsigned short* xb  = kvb + 2 * ND;
    unsigned short* wt  = xb + ND;                  // [2][4][128][128] bf16
    int* bucketcnt = (int*)(wt + 2 * 4 * 16384);    // [256]
    int* indptr    = bucketcnt + 256;               // [NN+1]
    int* esrc      = indptr + NN + 1;               // [EE]
    int2* bedge    = (int2*)(esrc + EE);            // [NBUK*BSTRIDE]
    float* gsum = (float*)(bedge + NBUK * BSTRIDE);
    float* gcnt = gsum + GG * DD;

    const int* src = ei;
    const int* dst = ei + EE;

    prep_kernel<<<1024, 256, 0, stream>>>(x, Wq, Wk, Wv, Ws, wt, xb, bucketcnt, gsum);
    bucket_kernel<<<256, 1024, 0, stream>>>(src, dst, bucketcnt, bedge);
    bsort_kernel<<<NBUK, 1024, 0, stream>>>(bucketcnt, bedge, indptr, esrc);

    for (int l = 0; l < 2; ++l) {
        size_t bo = (size_t)l * DD;
        const unsigned short* wtl = wt + (size_t)l * 4 * 16384;
        const unsigned short* xa = (l == 0) ? xb : hbuf;
        gemm_mfma<<<512, 256, 0, stream>>>(
            xa, wtl, bq + bo, bk + bo, bv + bo, bs + bo, qb, kvb, sb);
        attn_kernel<<<(NN + 3) / 4, 256, 0, stream>>>(
            qb, kvb, sb, indptr, esrc, hbuf, NN);
    }

    pool_kernel<<<(NN + PCHUNK - 1) / PCHUNK, 128, 0, stream>>>(hbuf, batch, gsum, gcnt, NN);
    head_kernel<<<GG, 64, 0, stream>>>(gsum, gcnt, Wfc, bfc, out);
}

// Round 14
// 283.260 us; speedup vs baseline: 1.2900x; 1.0081x over previous
//
#include <hip/hip_runtime.h>
#include <math.h>

#define NN 50000
#define EE 600000
#define DD 128
#define GG 64
#define NCLS 10
#define PCHUNK 128
#define NTILE (NN / 16)            // 3125 row-tiles, exact
#define NBUK 196                   // buckets of 256 dst nodes (dst>>8)
#define BSTRIDE 4096               // slots per bucket (mean 3072, sigma 55)
#define EPB ((EE + 255) / 256)     // 2344 edges per pass-1 block

typedef __attribute__((ext_vector_type(8))) __bf16 bf16x8;
typedef __attribute__((ext_vector_type(8))) unsigned short u16x8;
typedef __attribute__((ext_vector_type(4))) float f32x4;

__device__ __forceinline__ unsigned short f2bf(float f) {
    unsigned int u = __float_as_uint(f);
    u += 0x7fff + ((u >> 16) & 1);     // round-to-nearest-even
    return (unsigned short)(u >> 16);
}

__device__ __forceinline__ float bf2f(unsigned short h) {
    return __uint_as_float(((unsigned int)h) << 16);
}

// ---------------- fused prep: zero bucketcnt/gsum + wt convert --------------

__global__ __launch_bounds__(256) void prep_kernel(
    const float* __restrict__ wq, const float* __restrict__ wk,
    const float* __restrict__ wv, const float* __restrict__ ws,
    unsigned short* __restrict__ wt,
    int* __restrict__ bucketcnt, float* __restrict__ gsum) {
    int tid = blockIdx.x * 256 + threadIdx.x;
    int TOT = gridDim.x * 256;
    if (tid < 256) bucketcnt[tid] = 0;
    for (int i = tid; i < GG * DD + GG; i += TOT) gsum[i] = 0.f;
    for (int i = tid; i < 2 * 4 * 16384; i += TOT) {
        int k = i & 127;
        int n = (i >> 7) & 127;
        int lm = i >> 14;
        int l = lm >> 2, m = lm & 3;
        const float* w = (m == 0) ? wq : (m == 1) ? wk : (m == 2) ? wv : ws;
        wt[i] = f2bf(w[l * 16384 + k * 128 + n]);
    }
}

// ---------------- CSR pass 1: bucket by dst>>8 (LDS slots, 65k global atomics)

__global__ __launch_bounds__(1024) void bucket_kernel(
    const int* __restrict__ src, const int* __restrict__ dst,
    int* __restrict__ bucketcnt, int2* __restrict__ bedge) {
    __shared__ int hist[256];
    __shared__ int base[256];
    int t = threadIdx.x;
    if (t < 256) hist[t] = 0;
    __syncthreads();
    int e0 = blockIdx.x * EPB;
    int eend = min(e0 + EPB, EE);

    int b0 = -1, b1 = -1, b2 = -1;
    int sl0 = 0, sl1 = 0, sl2 = 0;
    int s0 = 0, s1 = 0, s2 = 0, d0 = 0, d1 = 0, d2 = 0;
    int i = e0 + t;
    if (i < eend) { d0 = dst[i]; s0 = src[i]; b0 = d0 >> 8; sl0 = atomicAdd(&hist[b0], 1); }
    i += 1024;
    if (i < eend) { d1 = dst[i]; s1 = src[i]; b1 = d1 >> 8; sl1 = atomicAdd(&hist[b1], 1); }
    i += 1024;
    if (i < eend) { d2 = dst[i]; s2 = src[i]; b2 = d2 >> 8; sl2 = atomicAdd(&hist[b2], 1); }
    __syncthreads();

    if (t < 256) {
        int h = hist[t];
        base[t] = h ? atomicAdd(&bucketcnt[t], h) : 0;
    }
    __syncthreads();

    if (b0 >= 0) bedge[b0 * BSTRIDE + base[b0] + sl0] = make_int2(s0, d0);
    if (b1 >= 0) bedge[b1 * BSTRIDE + base[b1] + sl1] = make_int2(s1, d1);
    if (b2 >= 0) bedge[b2 * BSTRIDE + base[b2] + sl2] = make_int2(s2, d2);
}

// ---------------- CSR pass 2: per-bucket node sort -> indptr + esrc ---------
// serial thread-0 prefixes replaced with wave-0 shfl scans (R13: ~1.5us each
// on every block's critical path).

__global__ __launch_bounds__(1024) void bsort_kernel(
    const int* __restrict__ bucketcnt, const int2* __restrict__ bedge,
    int* __restrict__ indptr, int* __restrict__ esrc) {
    __shared__ int buf[256];       // counts (bucket, then per-node histogram)
    __shared__ int cur[256];       // exclusive prefix / cursors
    int b = blockIdx.x;
    int t = threadIdx.x;

    if (t < 256) buf[t] = (t < NBUK) ? bucketcnt[t] : 0;
    __syncthreads();
    if (t < 64) {                  // wave-0 scan: buf -> cur (exclusive)
        int carry = 0;
        #pragma unroll
        for (int c = 0; c < 4; ++c) {
            int v = buf[c * 64 + t];
            int x = v;
            #pragma unroll
            for (int off = 1; off < 64; off <<= 1) {
                int y = __shfl_up(x, off);
                if (t >= off) x += y;
            }
            cur[c * 64 + t] = carry + x - v;
            carry += __shfl(x, 63);
        }
    }
    __syncthreads();
    int count = buf[b];
    int bstart = cur[b];
    int node0 = b << 8;
    int nn = min(256, NN - node0);
    if (b == 0 && t == 0) indptr[NN] = EE;
    __syncthreads();
    if (t < 256) buf[t] = 0;
    __syncthreads();

    const int2* be = bedge + (size_t)b * BSTRIDE;
    for (int i2 = t; i2 < count; i2 += 1024)
        atomicAdd(&buf[be[i2].y - node0], 1);
    __syncthreads();

    if (t < 64) {                  // wave-0 scan: buf -> cur (exclusive)
        int carry = 0;
        #pragma unroll
        for (int c = 0; c < 4; ++c) {
            int v = buf[c * 64 + t];
            int x = v;
            #pragma unroll
            for (int off = 1; off < 64; off <<= 1) {
                int y = __shfl_up(x, off);
                if (t >= off) x += y;
            }
            cur[c * 64 + t] = carry + x - v;
            carry += __shfl(x, 63);
        }
    }
    __syncthreads();
    if (t < nn) indptr[node0 + t] = bstart + cur[t];
    __syncthreads();               // indptr written before cur mutates

    for (int i2 = t; i2 < count; i2 += 1024) {
        int2 e = be[i2];
        int slot = atomicAdd(&cur[e.y - node0], 1);
        esrc[bstart + slot] = e.x;
    }
}

// ---------------- persistent-wave LDS-free bf16 MFMA GEMM (R10 winner) -----
// IN_BF16=false: layer-0 reads fp32 x directly (no xb conversion pass).
// k,v write into interleaved kv[node][256] (k at +0, v at +128).

template <bool IN_BF16>
__global__ __launch_bounds__(256, 4) void gemm_mfma(
    const void* __restrict__ xin,
    const unsigned short* __restrict__ wt,      // [4][128][128] bf16, n-major
    const float* __restrict__ bq, const float* __restrict__ bk,
    const float* __restrict__ bv, const float* __restrict__ bs,
    unsigned short* __restrict__ qb, unsigned short* __restrict__ kvb,
    unsigned short* __restrict__ sb) {
    int gw = blockIdx.x * 4 + (threadIdx.x >> 6);   // 0..2047
    int lane = threadIdx.x & 63;
    int mat = (gw >> 1) & 3;
    int ch = gw & 1;
    int wseq = gw >> 3;                              // 0..255
    int lr = lane & 15, quad = lane >> 4;

    const unsigned short* wm_ = wt + mat * 16384;
    const float* bias = (mat == 0) ? bq : (mat == 1) ? bk : (mat == 2) ? bv : bs;
    unsigned short* outp; int ostride, ooff;
    if (mat == 0)      { outp = qb;  ostride = 128; ooff = 0; }
    else if (mat == 1) { outp = kvb; ostride = 256; ooff = 0; }
    else if (mat == 2) { outp = kvb; ostride = 256; ooff = 128; }
    else               { outp = sb;  ostride = 128; ooff = 0; }

    bf16x8 bfr[4][4];
    #pragma unroll
    for (int ks = 0; ks < 4; ++ks)
        #pragma unroll
        for (int tn = 0; tn < 4; ++tn)
            bfr[ks][tn] = *(const bf16x8*)(wm_ + (ch * 64 + tn * 16 + lr) * 128
                                               + ks * 32 + quad * 8);
    float bcol[4];
    #pragma unroll
    for (int tn = 0; tn < 4; ++tn) bcol[tn] = bias[ch * 64 + tn * 16 + lr];

    for (int tile = wseq; tile < NTILE; tile += 256) {
        int row0 = tile * 16;
        bf16x8 af[4];
        #pragma unroll
        for (int ks = 0; ks < 4; ++ks) {
            if (IN_BF16) {
                af[ks] = *(const bf16x8*)((const unsigned short*)xin
                             + (size_t)(row0 + lr) * DD + ks * 32 + quad * 8);
            } else {
                const float* p = (const float*)xin
                                 + (size_t)(row0 + lr) * DD + ks * 32 + quad * 8;
                float4 f0 = *(const float4*)p;
                float4 f1 = *(const float4*)(p + 4);
                u16x8 a8;
                a8[0] = f2bf(f0.x); a8[1] = f2bf(f0.y); a8[2] = f2bf(f0.z); a8[3] = f2bf(f0.w);
                a8[4] = f2bf(f1.x); a8[5] = f2bf(f1.y); a8[6] = f2bf(f1.z); a8[7] = f2bf(f1.w);
                af[ks] = *(bf16x8*)&a8;
            }
        }

        f32x4 acc[4];
        #pragma unroll
        for (int tn = 0; tn < 4; ++tn) acc[tn] = (f32x4){0.f, 0.f, 0.f, 0.f};
        #pragma unroll
        for (int ks = 0; ks < 4; ++ks)
            #pragma unroll
            for (int tn = 0; tn < 4; ++tn)
                acc[tn] = __builtin_amdgcn_mfma_f32_16x16x32_bf16(
                    af[ks], bfr[ks][tn], acc[tn], 0, 0, 0);

        // C/D layout: col = lane&15, row = quad*4 + reg
        #pragma unroll
        for (int tn = 0; tn < 4; ++tn) {
            int col = ch * 64 + tn * 16 + lr;
            int nb = row0 + quad * 4;
            #pragma unroll
            for (int r = 0; r < 4; ++r)
                outp[(size_t)(nb + r) * ostride + ooff + col] = f2bf(acc[tn][r] + bcol[tn]);
        }
    }
}

// ---------------- fused online-softmax attention ----------------------------
// kv interleaved; 2-deep kv pipeline + esrc index prefetched 2 iterations
// ahead so the index load never serializes with the gather it feeds.

__global__ __launch_bounds__(256) void attn_kernel(
    const unsigned short* __restrict__ qb, const unsigned short* __restrict__ kvb,
    const unsigned short* __restrict__ sb,
    const int* __restrict__ indptr, const int* __restrict__ esrc,
    unsigned short* __restrict__ hout, int n) {
    int node = (int)((blockIdx.x * blockDim.x + threadIdx.x) >> 6);
    int lane = threadIdx.x & 63;
    if (node >= n) return;
    int g = lane >> 4, j = lane & 15;

    u16x8 q8 = *(const u16x8*)(qb + (size_t)node * DD + j * 8);
    float qf[8];
    #pragma unroll
    for (int c = 0; c < 8; ++c) qf[c] = bf2f(q8[c]);

    int beg = indptr[node], end = indptr[node + 1];

    float m = -3.0e38f, den = 0.f;
    float acc[8];
    #pragma unroll
    for (int c = 0; c < 8; ++c) acc[c] = 0.f;

    int e = beg + g;
    if (e < end) {
        int sidx = esrc[e];
        int en = e + 4;
        int sn = (en < end) ? esrc[en] : 0;          // index 1 ahead (resident)
        const unsigned short* p0 = kvb + (size_t)sidx * 256 + j * 8;
        u16x8 k8 = *(const u16x8*)p0;
        u16x8 v8 = *(const u16x8*)(p0 + 128);
        for (;;) {
            bool haven = en < end;
            int en2 = en + 4;
            int sn2 = (en2 < end) ? esrc[en2] : 0;   // index 2 ahead (loading)
            u16x8 k8n, v8n;
            if (haven) {
                const unsigned short* p = kvb + (size_t)sn * 256 + j * 8;
                k8n = *(const u16x8*)p;              // gather issues immediately:
                v8n = *(const u16x8*)(p + 128);      // sn already in a register
            }
            float p_;
            p_ = qf[0] * bf2f(k8[0]);
            p_ = fmaf(qf[1], bf2f(k8[1]), p_);
            p_ = fmaf(qf[2], bf2f(k8[2]), p_);
            p_ = fmaf(qf[3], bf2f(k8[3]), p_);
            p_ = fmaf(qf[4], bf2f(k8[4]), p_);
            p_ = fmaf(qf[5], bf2f(k8[5]), p_);
            p_ = fmaf(qf[6], bf2f(k8[6]), p_);
            p_ = fmaf(qf[7], bf2f(k8[7]), p_);
            p_ += __shfl_xor(p_, 8);
            p_ += __shfl_xor(p_, 4);
            p_ += __shfl_xor(p_, 2);
            p_ += __shfl_xor(p_, 1);
            float score = p_ * 0.088388347648318447f;   // 1/sqrt(128)
            float mn = fmaxf(m, score);
            float scale = __expf(m - mn);
            float pe = __expf(score - mn);
            den = den * scale + pe;
            #pragma unroll
            for (int c = 0; c < 8; ++c)
                acc[c] = fmaf(acc[c], scale, pe * bf2f(v8[c]));
            m = mn;
            if (!haven) break;
            en = en2; sn = sn2; k8 = k8n; v8 = v8n;
        }
    }

    float mo = __shfl_xor(m, 16);
    float m2 = fmaxf(m, mo);
    mo = __shfl_xor(m2, 32);
    float mf = fmaxf(m2, mo);
    float sc = __expf(m - mf);
    den *= sc;
    den += __shfl_xor(den, 16);
    den += __shfl_xor(den, 32);
    #pragma unroll
    for (int c = 0; c < 8; ++c) {
        float a = acc[c] * sc;
        a += __shfl_xor(a, 16);
        a += __shfl_xor(a, 32);
        acc[c] = a;
    }
    float inv = den > 0.f ? 1.0f / den : 0.f;
    if (g == 0) {
        u16x8 s8 = *(const u16x8*)(sb + (size_t)node * DD + j * 8);
        u16x8 o8;
        #pragma unroll
        for (int c = 0; c < 8; ++c)
            o8[c] = f2bf(fmaxf(fmaf(acc[c], inv, bf2f(s8[c])), 0.f));
        *(u16x8*)(hout + (size_t)node * DD + j * 8) = o8;
    }
}

// ---------------- global mean pool (h bf16): segmented running sum ----------

__global__ __launch_bounds__(128) void pool_kernel(const unsigned short* __restrict__ h,
                                                   const int* __restrict__ batch,
                                                   float* __restrict__ gsum,
                                                   float* __restrict__ gcnt, int n) {
    __shared__ int bsh[PCHUNK];
    int t = threadIdx.x;
    int node0 = blockIdx.x * PCHUNK;
    int nnodes = min(PCHUNK, n - node0);
    if (t < nnodes) bsh[t] = batch[node0 + t];
    __syncthreads();

    int cur = bsh[0];
    float acc = 0.f;
    int cnt = 0;
    for (int j = 0; j < nnodes; ++j) {
        int g = bsh[j];
        float val = bf2f(h[(size_t)(node0 + j) * DD + t]);
        if (g != cur) {
            atomicAdd(&gsum[cur * DD + t], acc);
            if (t == 0) atomicAdd(&gcnt[cur], (float)cnt);
            acc = 0.f; cnt = 0; cur = g;
        }
        acc += val; ++cnt;
    }
    if (cnt > 0) {
        atomicAdd(&gsum[cur * DD + t], acc);
        if (t == 0) atomicAdd(&gcnt[cur], (float)cnt);
    }
}

// ---------------- FC + log_softmax ----------------

__global__ __launch_bounds__(64) void head_kernel(
    const float* __restrict__ gsum, const float* __restrict__ gcnt,
    const float* __restrict__ wfc, const float* __restrict__ bfc,
    float* __restrict__ out) {
    int g = blockIdx.x;
    int lane = threadIdx.x;
    float cnt = fmaxf(gcnt[g], 1.0f);
    float inv = 1.0f / cnt;
    float p0 = gsum[g * DD + lane] * inv;
    float p1 = gsum[g * DD + lane + 64] * inv;
    __shared__ float logits[NCLS];
    for (int c = 0; c < NCLS; ++c) {
        float partial = p0 * wfc[lane * NCLS + c] + p1 * wfc[(lane + 64) * NCLS + c];
        partial += __shfl_xor(partial, 32);
        partial += __shfl_xor(partial, 16);
        partial += __shfl_xor(partial, 8);
        partial += __shfl_xor(partial, 4);
        partial += __shfl_xor(partial, 2);
        partial += __shfl_xor(partial, 1);
        if (lane == 0) logits[c] = partial + bfc[c];
    }
    __syncthreads();
    if (lane == 0) {
        float mx = logits[0];
        for (int c = 1; c < NCLS; ++c) mx = fmaxf(mx, logits[c]);
        float sum = 0.f;
        for (int c = 0; c < NCLS; ++c) sum += expf(logits[c] - mx);
        float lse = mx + logf(sum);
        for (int c = 0; c < NCLS; ++c) out[g * NCLS + c] = logits[c] - lse;
    }
}

// ---------------- launch ----------------

extern "C" void kernel_launch(void* const* d_in, const int* in_sizes, int n_in,
                              void* d_out, int out_size, void* d_ws, size_t ws_size,
                              hipStream_t stream) {
    const float* x     = (const float*)d_in[0];
    const int*   ei    = (const int*)d_in[1];
    const int*   batch = (const int*)d_in[2];
    const float* Wq = (const float*)d_in[3];
    const float* bq = (const float*)d_in[4];
    const float* Wk = (const float*)d_in[5];
    const float* bk = (const float*)d_in[6];
    const float* Wv = (const float*)d_in[7];
    const float* bv = (const float*)d_in[8];
    const float* Ws = (const float*)d_in[9];
    const float* bs = (const float*)d_in[10];
    const float* Wfc = (const float*)d_in[11];
    const float* bfc = (const float*)d_in[12];
    float* out = (float*)d_out;

    const size_t ND = (size_t)NN * DD;
    unsigned short* hbuf = (unsigned short*)d_ws;   // all bf16
    unsigned short* qb  = hbuf + ND;
    unsigned short* sb  = qb + ND;
    unsigned short* kvb = sb + ND;                  // [NN][256]: k | v interleaved
    unsigned short* wt  = kvb + 2 * ND;             // [2][4][128][128] bf16
    int* bucketcnt = (int*)(wt + 2 * 4 * 16384);    // [256]
    int* indptr    = bucketcnt + 256;               // [NN+1]
    int* esrc      = indptr + NN + 1;               // [EE]
    int2* bedge    = (int2*)(esrc + EE);            // [NBUK*BSTRIDE]
    float* gsum = (float*)(bedge + NBUK * BSTRIDE);
    float* gcnt = gsum + GG * DD;

    const int* src = ei;
    const int* dst = ei + EE;

    prep_kernel<<<256, 256, 0, stream>>>(Wq, Wk, Wv, Ws, wt, bucketcnt, gsum);
    bucket_kernel<<<256, 1024, 0, stream>>>(src, dst, bucketcnt, bedge);
    bsort_kernel<<<NBUK, 1024, 0, stream>>>(bucketcnt, bedge, indptr, esrc);

    for (int l = 0; l < 2; ++l) {
        size_t bo = (size_t)l * DD;
        const unsigned short* wtl = wt + (size_t)l * 4 * 16384;
        if (l == 0)
            gemm_mfma<false><<<512, 256, 0, stream>>>(
                (const void*)x, wtl, bq + bo, bk + bo, bv + bo, bs + bo,
                qb, kvb, sb);
        else
            gemm_mfma<true><<<512, 256, 0, stream>>>(
                (const void*)hbuf, wtl, bq + bo, bk + bo, bv + bo, bs + bo,
                qb, kvb, sb);
        attn_kernel<<<(NN + 3) / 4, 256, 0, stream>>>(
            qb, kvb, sb, indptr, esrc, hbuf, NN);
    }

    pool_kernel<<<(NN + PCHUNK - 1) / PCHUNK, 128, 0, stream>>>(hbuf, batch, gsum, gcnt, NN);
    head_kernel<<<GG, 64, 0, stream>>>(gsum, gcnt, Wfc, bfc, out);
}